// Round 10
// baseline (1847.039 us; speedup 1.0000x reference)
//
#include <hip/hip_runtime.h>
#include <hip/hip_bf16.h>
#include <math.h>

#define N_NODES 100000
#define N_EDGES 1600000
#define SCAN_B 1024
#define SCAN_NB ((N_NODES + SCAN_B - 1) / SCAN_B)

typedef short s16x8 __attribute__((ext_vector_type(8)));
typedef float f32x4 __attribute__((ext_vector_type(4)));
typedef unsigned short u16;
typedef u16 u16x8 __attribute__((ext_vector_type(8)));
typedef u16 u16x4 __attribute__((ext_vector_type(4)));

__device__ __forceinline__ u16 f2bf_rn(float f) {
  union { float f; unsigned u; } x; x.f = f;
  unsigned u = x.u + 0x7fffu + ((x.u >> 16) & 1u);
  return (u16)(u >> 16);
}

// async global->LDS, 16B per lane; LDS dest = wave-uniform base + lane*16
__device__ __forceinline__ void gload16(const void* g, void* l) {
  __builtin_amdgcn_global_load_lds(
      (const __attribute__((address_space(1))) void*)g,
      (__attribute__((address_space(3))) void*)l, 16, 0, 0);
}

// ---------------- graph prep ----------------

__global__ void k_count(const int* __restrict__ src, const int* __restrict__ dst,
                        int* __restrict__ deg_out, int* __restrict__ deg_in) {
  int i = blockIdx.x * blockDim.x + threadIdx.x;
  int stride = gridDim.x * blockDim.x;
  for (; i < N_EDGES; i += stride) {
    atomicAdd(&deg_out[src[i]], 1);
    atomicAdd(&deg_in[dst[i]], 1);
  }
}

__global__ void k_norms(const int* __restrict__ deg_out, const int* __restrict__ deg_in,
                        float* __restrict__ norm_out, float* __restrict__ norm_in) {
  int i = blockIdx.x * blockDim.x + threadIdx.x;
  if (i < N_NODES) {
    int a = deg_out[i], b = deg_in[i];
    norm_out[i] = a > 0 ? rsqrtf((float)a) : 0.f;
    norm_in[i]  = b > 0 ? rsqrtf((float)b) : 0.f;
  }
}

// hierarchical scan: block sums -> scan sums -> local scan + base
__global__ __launch_bounds__(1024) void k_scan1(const int* __restrict__ deg,
                                                int* __restrict__ bsum) {
  __shared__ int red[16];
  int b = blockIdx.x, t = threadIdx.x;
  int i = b * SCAN_B + t;
  int x = (i < N_NODES) ? deg[i] : 0;
#pragma unroll
  for (int o = 32; o > 0; o >>= 1) x += __shfl_down(x, o, 64);
  if ((t & 63) == 0) red[t >> 6] = x;
  __syncthreads();
  if (t == 0) {
    int s = 0;
#pragma unroll
    for (int j = 0; j < 16; ++j) s += red[j];
    bsum[b] = s;
  }
}

__global__ __launch_bounds__(128) void k_scan2(const int* __restrict__ bsum,
                                               int* __restrict__ boffs) {
  __shared__ int buf[128];
  int t = threadIdx.x;
  int x = (t < SCAN_NB) ? bsum[t] : 0;
  buf[t] = x;
  __syncthreads();
  for (int off = 1; off < 128; off <<= 1) {
    int v = (t >= off) ? buf[t - off] : 0;
    __syncthreads();
    buf[t] += v;
    __syncthreads();
  }
  if (t < SCAN_NB) boffs[t] = (t > 0) ? buf[t - 1] : 0;
}

__global__ __launch_bounds__(1024) void k_scan3(const int* __restrict__ deg,
                                                const int* __restrict__ boffs,
                                                int* __restrict__ row_ptr) {
  __shared__ int buf[SCAN_B];
  int b = blockIdx.x, t = threadIdx.x;
  int i = b * SCAN_B + t;
  int x = (i < N_NODES) ? deg[i] : 0;
  buf[t] = x;
  __syncthreads();
  for (int off = 1; off < SCAN_B; off <<= 1) {
    int v = (t >= off) ? buf[t - off] : 0;
    __syncthreads();
    buf[t] += v;
    __syncthreads();
  }
  if (i < N_NODES) row_ptr[i + 1] = boffs[b] + buf[t];
  if (i == 0) row_ptr[0] = 0;
}

__global__ void k_fill(const int* __restrict__ src, const int* __restrict__ dst,
                       const int* __restrict__ row_ptr, int* __restrict__ cursor,
                       int* __restrict__ csr_src) {
  int i = blockIdx.x * blockDim.x + threadIdx.x;
  int stride = gridDim.x * blockDim.x;
  for (; i < N_EDGES; i += stride) {
    int d = dst[i];
    int p = atomicAdd(&cursor[d], 1);
    csr_src[row_ptr[d] + p] = src[i];
  }
}

// transpose + hi/lo split of a weight matrix: W[K][N] f32 -> Wt_hi/lo[NB][K] bf16
__global__ void k_wsplit(const float* __restrict__ W, int K, int N, int NB,
                         u16* __restrict__ Wth, u16* __restrict__ Wtl) {
  int i = blockIdx.x * blockDim.x + threadIdx.x;
  if (i >= NB * K) return;
  int col = i / K, k = i - col * K;
  float v = (col < N) ? W[(size_t)k * N + col] : 0.f;
  union { float f; unsigned u; } x; x.f = v;
  u16 h = (u16)(x.u >> 16);
  union { unsigned u; float f; } hf; hf.u = (unsigned)h << 16;
  Wth[i] = h;
  Wtl[i] = f2bf_rn(v - hf.f);
}

// ---------------- pipelined MFMA GEMM, 64x128 tile (bf16-plane A path) ----------------
// LDS [buf2][block][kchunk4][row16][8 u16]: staging (global_load_lds, lane*16) and
// fragment ds_read_b128 both linear -> zero bank conflicts. 4 waves = 2rx2c of
// 32x64 output, acc[2][4]. 6 gload16/wave/step -> counted vmcnt(6) dbuf pipeline.
// Raw s_barrier (NOT __syncthreads, which drains vmcnt to 0).
// NBCOL==2: ids p and p+8 (same XCD, round-robin) share a row-stripe -> A L2 hit.

template <int NBCOL, int OUTBF>
__global__ __launch_bounds__(256) void k_gemm_p(
    const u16* __restrict__ Ah, const u16* __restrict__ Al, int K,
    const u16* __restrict__ Bh, const u16* __restrict__ Bl,
    void* __restrict__ Cv, int ldc, int M, int Ncols, int NBrow) {
  __shared__ u16 sAh[2][4][4][16][8];
  __shared__ u16 sAl[2][4][4][16][8];
  __shared__ u16 sBh[2][8][4][16][8];
  __shared__ u16 sBl[2][8][4][16][8];

  int p = blockIdx.x;
  int row, col;
  if (NBCOL == 2) {
    int nb = NBrow * 2;
    int cut = (nb >> 4) << 4;
    if (p < cut) { row = ((p >> 4) << 3) + (p & 7); col = (p >> 3) & 1; }
    else { int q = p - cut; row = (cut >> 1) + (q >> 1); col = q & 1; }
  } else { row = p; col = 0; }
  int rowBase = row * 64;
  int colBase = col * 128;

  int t = threadIdx.x;
  int w = t >> 6, l = t & 63;
  int lr = l & 15;   // row within 16-row block (staging AND fragment)
  int kc = l >> 4;   // k-chunk 0..3 (16B)

  int gaR  = min(rowBase + w * 16 + lr, M - 1);
  int gbR0 = colBase + w * 16 + lr;
  int gbR1 = colBase + (4 + w) * 16 + lr;

  const u16* pAh  = Ah + (size_t)gaR * K + kc * 8;
  const u16* pAl  = Al + (size_t)gaR * K + kc * 8;
  const u16* pBh0 = Bh + (size_t)gbR0 * K + kc * 8;
  const u16* pBh1 = Bh + (size_t)gbR1 * K + kc * 8;
  const u16* pBl0 = Bl + (size_t)gbR0 * K + kc * 8;
  const u16* pBl1 = Bl + (size_t)gbR1 * K + kc * 8;

  int wrw = w >> 1, wcw = w & 1;   // wave output: rows wrw*32..+31, cols wcw*64..+63
  int crow = kc * 4;

  f32x4 acc[2][4];
#pragma unroll
  for (int r = 0; r < 2; ++r)
#pragma unroll
    for (int c = 0; c < 4; ++c) acc[r][c] = (f32x4)(0.f);

  auto stage = [&](int bb, int k0) {
    gload16(pAh + k0, &sAh[bb][w][0][0][0]);
    gload16(pAl + k0, &sAl[bb][w][0][0][0]);
    gload16(pBh0 + k0, &sBh[bb][w][0][0][0]);
    gload16(pBh1 + k0, &sBh[bb][4 + w][0][0][0]);
    gload16(pBl0 + k0, &sBl[bb][w][0][0][0]);
    gload16(pBl1 + k0, &sBl[bb][4 + w][0][0][0]);
  };

  int NS = K >> 5;
  stage(0, 0);
  for (int s = 0; s < NS; ++s) {
    int bb = s & 1;
    if (s + 1 < NS) {
      stage(bb ^ 1, (s + 1) * 32);
      asm volatile("s_waitcnt vmcnt(6)" ::: "memory");
    } else {
      asm volatile("s_waitcnt vmcnt(0)" ::: "memory");
    }
    __builtin_amdgcn_s_barrier();

    s16x8 ah[2], al[2], bh[4], bl[4];
#pragma unroll
    for (int r = 0; r < 2; ++r) {
      ah[r] = *(const s16x8*)&sAh[bb][wrw * 2 + r][kc][lr][0];
      al[r] = *(const s16x8*)&sAl[bb][wrw * 2 + r][kc][lr][0];
    }
#pragma unroll
    for (int c = 0; c < 4; ++c) {
      bh[c] = *(const s16x8*)&sBh[bb][wcw * 4 + c][kc][lr][0];
      bl[c] = *(const s16x8*)&sBl[bb][wcw * 4 + c][kc][lr][0];
    }
#pragma unroll
    for (int r = 0; r < 2; ++r)
#pragma unroll
      for (int c = 0; c < 4; ++c)
        acc[r][c] = __builtin_amdgcn_mfma_f32_16x16x32_bf16(ah[r], bh[c], acc[r][c], 0, 0, 0);
#pragma unroll
    for (int r = 0; r < 2; ++r)
#pragma unroll
      for (int c = 0; c < 4; ++c)
        acc[r][c] = __builtin_amdgcn_mfma_f32_16x16x32_bf16(ah[r], bl[c], acc[r][c], 0, 0, 0);
#pragma unroll
    for (int r = 0; r < 2; ++r)
#pragma unroll
      for (int c = 0; c < 4; ++c)
        acc[r][c] = __builtin_amdgcn_mfma_f32_16x16x32_bf16(al[r], bh[c], acc[r][c], 0, 0, 0);

    __builtin_amdgcn_s_barrier();
  }

#pragma unroll
  for (int r = 0; r < 2; ++r)
#pragma unroll
    for (int c = 0; c < 4; ++c) {
      int ccol = colBase + wcw * 64 + c * 16 + lr;
      if (ccol < Ncols) {
#pragma unroll
        for (int j = 0; j < 4; ++j) {
          int rrow = rowBase + wrw * 32 + r * 16 + crow + j;
          if (rrow < M) {
            if (OUTBF) ((u16*)Cv)[(size_t)rrow * ldc + ccol] = f2bf_rn(acc[r][c][j]);
            else       ((float*)Cv)[(size_t)rrow * ldc + ccol] = acc[r][c][j];
          }
        }
      }
    }
}

// ---------------- layer-0 GEMM: 64x128 tile, f32 A in-register split ----------------

__global__ __launch_bounds__(256) void k_gemm_l0(
    const float* __restrict__ Af, int K,
    const u16* __restrict__ Bh, const u16* __restrict__ Bl,
    const float* __restrict__ rowscale,
    u16* __restrict__ C, int ldc, int M, int Ncols) {
  __shared__ u16 sAh[4][4][16][8];
  __shared__ u16 sAl[4][4][16][8];
  __shared__ u16 sBh[8][4][16][8];
  __shared__ u16 sBl[8][4][16][8];

  int t = threadIdx.x;
  int colBase = blockIdx.x * 128;
  int rowBase = blockIdx.y * 64;

  int w = t >> 6, l = t & 63;
  int lr = l & 15;
  int kc = l >> 4;

  int gaR  = min(rowBase + w * 16 + lr, M - 1);
  int gbR0 = colBase + w * 16 + lr;
  int gbR1 = colBase + (4 + w) * 16 + lr;

  float rs = rowscale[gaR];

  int wrw = w >> 1, wcw = w & 1;
  int crow = kc * 4;

  f32x4 acc[2][4];
#pragma unroll
  for (int r = 0; r < 2; ++r)
#pragma unroll
    for (int c = 0; c < 4; ++c) acc[r][c] = (f32x4)(0.f);

  for (int k0 = 0; k0 < K; k0 += 32) {
    __syncthreads();
    {
      const float* p0 = Af + (size_t)gaR * K + k0 + kc * 8;
      float4 v0 = *(const float4*)p0;
      float4 v1 = *(const float4*)(p0 + 4);
      float vv[8] = {v0.x * rs, v0.y * rs, v0.z * rs, v0.w * rs,
                     v1.x * rs, v1.y * rs, v1.z * rs, v1.w * rs};
      u16x8 hi, lo;
#pragma unroll
      for (int i = 0; i < 8; ++i) {
        union { float f; unsigned u; } x; x.f = vv[i];
        hi[i] = (u16)(x.u >> 16);
        union { unsigned u; float f; } hf; hf.u = x.u & 0xffff0000u;
        lo[i] = f2bf_rn(vv[i] - hf.f);
      }
      *(u16x8*)&sAh[w][kc][lr][0] = hi;
      *(u16x8*)&sAl[w][kc][lr][0] = lo;
    }
    gload16(Bh + (size_t)gbR0 * K + k0 + kc * 8, &sBh[w][0][0][0]);
    gload16(Bh + (size_t)gbR1 * K + k0 + kc * 8, &sBh[4 + w][0][0][0]);
    gload16(Bl + (size_t)gbR0 * K + k0 + kc * 8, &sBl[w][0][0][0]);
    gload16(Bl + (size_t)gbR1 * K + k0 + kc * 8, &sBl[4 + w][0][0][0]);
    __syncthreads();

    s16x8 ah[2], al[2], bh[4], bl[4];
#pragma unroll
    for (int r = 0; r < 2; ++r) {
      ah[r] = *(const s16x8*)&sAh[wrw * 2 + r][kc][lr][0];
      al[r] = *(const s16x8*)&sAl[wrw * 2 + r][kc][lr][0];
    }
#pragma unroll
    for (int c = 0; c < 4; ++c) {
      bh[c] = *(const s16x8*)&sBh[wcw * 4 + c][kc][lr][0];
      bl[c] = *(const s16x8*)&sBl[wcw * 4 + c][kc][lr][0];
    }
#pragma unroll
    for (int r = 0; r < 2; ++r)
#pragma unroll
      for (int c = 0; c < 4; ++c)
        acc[r][c] = __builtin_amdgcn_mfma_f32_16x16x32_bf16(ah[r], bh[c], acc[r][c], 0, 0, 0);
#pragma unroll
    for (int r = 0; r < 2; ++r)
#pragma unroll
      for (int c = 0; c < 4; ++c)
        acc[r][c] = __builtin_amdgcn_mfma_f32_16x16x32_bf16(ah[r], bl[c], acc[r][c], 0, 0, 0);
#pragma unroll
    for (int r = 0; r < 2; ++r)
#pragma unroll
      for (int c = 0; c < 4; ++c)
        acc[r][c] = __builtin_amdgcn_mfma_f32_16x16x32_bf16(al[r], bh[c], acc[r][c], 0, 0, 0);
  }

#pragma unroll
  for (int r = 0; r < 2; ++r)
#pragma unroll
    for (int c = 0; c < 4; ++c) {
      int col = colBase + wcw * 64 + c * 16 + lr;
      if (col < Ncols) {
#pragma unroll
        for (int j = 0; j < 4; ++j) {
          int row = rowBase + wrw * 32 + r * 16 + crow + j;
          if (row < M) C[(size_t)row * ldc + col] = f2bf_rn(acc[r][c][j]);
        }
      }
    }
}

// ---------------- CSR aggregation: wave per node, lane owns 4 cols ----------------
// proj is bf16 (8B/lane/edge gather); accumulate f32.
// mode 0: jk = v.  mode 1: jk = max(jk,v).  mode 2: jv = max(jk,v), planes from jv.

__global__ __launch_bounds__(256) void k_agg(const u16* __restrict__ proj,
                                             const int* __restrict__ row_ptr,
                                             const int* __restrict__ csr_src,
                                             const float* __restrict__ norm_in,
                                             const float* __restrict__ norm_out,
                                             const float* __restrict__ bias,
                                             u16* __restrict__ hHi, u16* __restrict__ hLo,
                                             float* __restrict__ jk, int mode) {
  int wid = __builtin_amdgcn_readfirstlane(threadIdx.x >> 6);
  int node = blockIdx.x * 4 + wid;
  if (node >= N_NODES) return;
  int l4 = (threadIdx.x & 63) * 4;

  int s = row_ptr[node], e = row_ptr[node + 1];
  f32x4 a0 = (f32x4)(0.f), a1 = (f32x4)(0.f), a2 = (f32x4)(0.f), a3 = (f32x4)(0.f);
  int i = s;
  for (; i + 3 < e; i += 4) {
    u16x4 r0 = *(const u16x4*)(proj + (size_t)csr_src[i] * 256 + l4);
    u16x4 r1 = *(const u16x4*)(proj + (size_t)csr_src[i + 1] * 256 + l4);
    u16x4 r2 = *(const u16x4*)(proj + (size_t)csr_src[i + 2] * 256 + l4);
    u16x4 r3 = *(const u16x4*)(proj + (size_t)csr_src[i + 3] * 256 + l4);
#pragma unroll
    for (int j = 0; j < 4; ++j) {
      union { unsigned u; float f; } x0, x1, x2, x3;
      x0.u = (unsigned)r0[j] << 16; a0[j] += x0.f;
      x1.u = (unsigned)r1[j] << 16; a1[j] += x1.f;
      x2.u = (unsigned)r2[j] << 16; a2[j] += x2.f;
      x3.u = (unsigned)r3[j] << 16; a3[j] += x3.f;
    }
  }
  for (; i < e; ++i) {
    u16x4 r0 = *(const u16x4*)(proj + (size_t)csr_src[i] * 256 + l4);
#pragma unroll
    for (int j = 0; j < 4; ++j) {
      union { unsigned u; float f; } x0;
      x0.u = (unsigned)r0[j] << 16; a0[j] += x0.f;
    }
  }

  float nin = norm_in[node];
  f32x4 b4 = *(const f32x4*)(bias + l4);
  f32x4 v = ((a0 + a1) + (a2 + a3)) * nin + b4;
#pragma unroll
  for (int j = 0; j < 4; ++j) v[j] = fmaxf(v[j], 0.f);

  size_t idx = (size_t)node * 256 + l4;
  f32x4 pv = v;
  if (mode == 0) {
    __builtin_nontemporal_store(v[0], jk + idx + 0);
    __builtin_nontemporal_store(v[1], jk + idx + 1);
    __builtin_nontemporal_store(v[2], jk + idx + 2);
    __builtin_nontemporal_store(v[3], jk + idx + 3);
  } else {
    f32x4 jold;
    jold[0] = __builtin_nontemporal_load(jk + idx + 0);
    jold[1] = __builtin_nontemporal_load(jk + idx + 1);
    jold[2] = __builtin_nontemporal_load(jk + idx + 2);
    jold[3] = __builtin_nontemporal_load(jk + idx + 3);
    f32x4 jv;
#pragma unroll
    for (int j = 0; j < 4; ++j) jv[j] = fmaxf(jold[j], v[j]);
    if (mode == 1) {
      __builtin_nontemporal_store(jv[0], jk + idx + 0);
      __builtin_nontemporal_store(jv[1], jk + idx + 1);
      __builtin_nontemporal_store(jv[2], jk + idx + 2);
      __builtin_nontemporal_store(jv[3], jk + idx + 3);
    } else {
      pv = jv;
    }
  }

  float nout = norm_out[node];
  u16x4 hi, lo;
#pragma unroll
  for (int j = 0; j < 4; ++j) {
    float sv = pv[j] * nout;
    union { float f; unsigned u; } x; x.f = sv;
    hi[j] = (u16)(x.u >> 16);
    union { unsigned u; float f; } hf; hf.u = x.u & 0xffff0000u;
    lo[j] = f2bf_rn(sv - hf.f);
  }
  *(u16x4*)(hHi + idx) = hi;
  *(u16x4*)(hLo + idx) = lo;
}

// ---------------- final 40-dim aggregation + log_softmax ----------------

__global__ __launch_bounds__(64) void k_agg_out(const float* __restrict__ proj,
                                                const int* __restrict__ row_ptr,
                                                const int* __restrict__ csr_src,
                                                const float* __restrict__ norm_in,
                                                const float* __restrict__ b_out,
                                                float* __restrict__ out) {
  int n = blockIdx.x;
  int c = threadIdx.x;  // 64 threads, cols 0..39 live
  int s = row_ptr[n], e = row_ptr[n + 1];
  float acc = 0.f;
  for (int i = s; i < e; ++i) {
    acc += proj[(size_t)csr_src[i] * 64 + c];
  }
  float v = acc * norm_in[n] + ((c < 40) ? b_out[c] : 0.f);
  float vm = (c < 40) ? v : -3.0e38f;
  float m = vm;
#pragma unroll
  for (int o = 32; o > 0; o >>= 1) m = fmaxf(m, __shfl_xor(m, o, 64));
  float ex = (c < 40) ? __expf(v - m) : 0.f;
  float ssum = ex;
#pragma unroll
  for (int o = 32; o > 0; o >>= 1) ssum += __shfl_xor(ssum, o, 64);
  float lse = m + logf(ssum);
  if (c < 40) out[(size_t)n * 40 + c] = v - lse;
}

// ---------------- launch ----------------

extern "C" void kernel_launch(void* const* d_in, const int* in_sizes, int n_in,
                              void* d_out, int out_size, void* d_ws, size_t ws_size,
                              hipStream_t stream) {
  const float* feats = (const float*)d_in[0];
  const int*   src   = (const int*)d_in[1];
  const int*   dst   = (const int*)d_in[2];
  const float* W0    = (const float*)d_in[3];
  const float* b0    = (const float*)d_in[4];
  const float* Ws    = (const float*)d_in[5];
  const float* bs    = (const float*)d_in[6];
  const float* W_out = (const float*)d_in[7];
  const float* b_out = (const float*)d_in[8];
  float* out = (float*)d_out;

  char* base = (char*)d_ws;
  size_t off = 0;
  auto alloc = [&](size_t bytes) -> void* {
    off = (off + 255) & ~(size_t)255;
    void* r = base + off;
    off += bytes;
    return r;
  };
  float* norm_out = (float*)alloc((size_t)N_NODES * 4);
  float* norm_in  = (float*)alloc((size_t)N_NODES * 4);
  int*   deg_out  = (int*)alloc((size_t)N_NODES * 4);
  int*   deg_in   = (int*)alloc((size_t)N_NODES * 4);
  int*   cursor   = (int*)alloc((size_t)N_NODES * 4);
  int*   row_ptr  = (int*)alloc((size_t)(N_NODES + 1) * 4);
  int*   bsum     = (int*)alloc((size_t)SCAN_NB * 4);
  int*   boffs    = (int*)alloc((size_t)SCAN_NB * 4);
  int*   csr_src  = (int*)alloc((size_t)N_EDGES * 4);
  u16*   Wt0h     = (u16*)alloc((size_t)256 * 512 * 2);
  u16*   Wt0l     = (u16*)alloc((size_t)256 * 512 * 2);
  u16*   Wtsh     = (u16*)alloc((size_t)5 * 256 * 256 * 2);
  u16*   Wtsl     = (u16*)alloc((size_t)5 * 256 * 256 * 2);
  u16*   Wtoh     = (u16*)alloc((size_t)128 * 256 * 2);
  u16*   Wtol     = (u16*)alloc((size_t)128 * 256 * 2);
  float* proj40   = (float*)alloc((size_t)N_NODES * 64 * 4);
  u16*   hHi      = (u16*)alloc((size_t)N_NODES * 256 * 2);
  u16*   hLo      = (u16*)alloc((size_t)N_NODES * 256 * 2);
  u16*   bufC     = (u16*)alloc((size_t)N_NODES * 256 * 2);
  float* jk       = (float*)alloc((size_t)N_NODES * 256 * 4);
  (void)ws_size; (void)in_sizes; (void)n_in; (void)out_size;

  hipMemsetAsync(deg_out, 0, (size_t)N_NODES * 4, stream);
  hipMemsetAsync(deg_in,  0, (size_t)N_NODES * 4, stream);
  hipMemsetAsync(cursor,  0, (size_t)N_NODES * 4, stream);

  k_count<<<2048, 256, 0, stream>>>(src, dst, deg_out, deg_in);
  k_norms<<<(N_NODES + 255) / 256, 256, 0, stream>>>(deg_out, deg_in, norm_out, norm_in);
  k_scan1<<<SCAN_NB, 1024, 0, stream>>>(deg_in, bsum);
  k_scan2<<<1, 128, 0, stream>>>(bsum, boffs);
  k_scan3<<<SCAN_NB, 1024, 0, stream>>>(deg_in, boffs, row_ptr);
  k_fill<<<2048, 256, 0, stream>>>(src, dst, row_ptr, cursor, csr_src);

  k_wsplit<<<(256 * 512 + 255) / 256, 256, 0, stream>>>(W0, 512, 256, 256, Wt0h, Wt0l);
  for (int ll = 0; ll < 5; ++ll)
    k_wsplit<<<(256 * 256 + 255) / 256, 256, 0, stream>>>(
        Ws + (size_t)ll * 256 * 256, 256, 256, 256,
        Wtsh + (size_t)ll * 256 * 256, Wtsl + (size_t)ll * 256 * 256);
  k_wsplit<<<(128 * 256 + 255) / 256, 256, 0, stream>>>(W_out, 256, 40, 128, Wtoh, Wtol);

  const int NBROW = (N_NODES + 63) / 64;  // 1563
  dim3 ga((N_NODES + 3) / 4);
  // layer 0 (K=512, f32 A path with in-register split + rowscale)
  k_gemm_l0<<<dim3(2, NBROW), 256, 0, stream>>>(feats, 512, Wt0h, Wt0l,
                                                norm_out, bufC, 256, N_NODES, 256);
  k_agg<<<ga, 256, 0, stream>>>(bufC, row_ptr, csr_src, norm_in, norm_out, b0,
                                hHi, hLo, jk, 0);
  // layers 1..5 (K=256, plane A path, pipelined + XCD pair-swizzle)
  for (int ll = 0; ll < 5; ++ll) {
    k_gemm_p<2, 1><<<NBROW * 2, 256, 0, stream>>>(hHi, hLo, 256,
                                                  Wtsh + (size_t)ll * 256 * 256,
                                                  Wtsl + (size_t)ll * 256 * 256,
                                                  bufC, 256, N_NODES, 256, NBROW);
    int mode = (ll == 4) ? 2 : 1;
    const float* bias = bs + (size_t)ll * 256;
    k_agg<<<ga, 256, 0, stream>>>(bufC, row_ptr, csr_src, norm_in, norm_out, bias,
                                  hHi, hLo, jk, mode);
  }
  // final: jk planes (mode-2 agg) @ W_out, aggregate, log_softmax
  k_gemm_p<1, 0><<<NBROW, 256, 0, stream>>>(hHi, hLo, 256, Wtoh, Wtol,
                                            proj40, 64, N_NODES, 64, NBROW);
  k_agg_out<<<N_NODES, 64, 0, stream>>>(proj40, row_ptr, csr_src, norm_in, b_out, out);
}